// Round 9
// baseline (88.284 us; speedup 1.0000x reference)
//
#include <hip/hip_runtime.h>

typedef _Float16 half8 __attribute__((ext_vector_type(8)));
typedef float floatx4 __attribute__((ext_vector_type(4)));

#define PI_F 3.14159265358979323846f
#define LSTR 72

// ===================== Kernel 1: K f16 build from closed form (validated R7/R8):
// K[i][j] = c[(i-j)&1023]; c[0]=0.5, c[even]=0, c[odd d] = -1/(524288 sin^2(pi d/1024))
__global__ __launch_bounds__(256) void build_K_kernel(_Float16* __restrict__ K_ws) {
  const int base = ((int)blockIdx.x << 11) + ((int)threadIdx.x << 3);
  const int i = base >> 9;
  const int j0 = base & 511;
  _Float16 vals[8];
#pragma unroll
  for (int jj = 0; jj < 8; ++jj) {
    int d = (i - (j0 + jj)) & 1023;
    float v;
    if (d == 0) {
      v = 0.5f;
    } else if (d & 1) {
      float sn = __sinf((float)d * (PI_F / 1024.0f));
      v = -1.0f / (524288.0f * sn * sn);
    } else {
      v = 0.0f;
    }
    vals[jj] = (_Float16)v;
  }
  *(uint4*)(K_ws + base) = *(const uint4*)vals;
}

// ===================== Kernel 2: fused transpose+GEMM, double-buffered.
// Operands SWAPPED vs R8: A = x as [a][s] (in-register transpose stage),
// B = K rows [s'][s] (coalesced stage). C/D: col=s', reg-quad = 4 consecutive a
// -> dwordx4 epilogue stores. Block = 128 thr (2 waves), tile M(a)=64 x N(s')=128,
// wave tile 64x64 (4x4 frags, halved fragment traffic per MFMA). Grid 512
// (bc16 x st4 x at8), 2 blocks/CU (55.3 KB LDS). XCD swizzle: same (bc,at)
// share blk%8 -> x slice re-reads hit same XCD L2.
__global__ __launch_bounds__(128, 2) void gemm_fused_kernel(
    const _Float16* __restrict__ K_ws, const float* __restrict__ x,
    float* __restrict__ out) {
  __shared__ __align__(16) _Float16 lX[2][64 * LSTR];   // 2 x  9.2 KB, [a][k]
  __shared__ __align__(16) _Float16 lK[2][128 * LSTR];  // 2 x 18.4 KB, [s'][k]

  const int t = threadIdx.x;
  const int raw = blockIdx.x;
  const int at = raw & 7;
  const int qq = raw >> 3;
  const int st = qq & 3;
  const int bc = qq >> 2;
  const int a0 = at << 6, s0 = st << 7;

  const int w = t >> 6, lane = t & 63;
  const int n_w = w << 6;  // wave s'-offset: 0 / 64
  const int fl = lane & 15, q4 = lane >> 4;

  // staging indices: K rows (p<<4)+(t>>3), chunk t&7; x k-quads (t>>4)+(p<<3), a-quad t&15
  const int krow = t >> 3, cc0 = t & 7;
  const int aq = t & 15;

  const float4* __restrict__ x4 = (const float4*)x;
  const int xq_base = (bc * 262144 + a0) >> 2;  // float4 index base

  floatx4 acc[4][4] = {};

  // ---- prologue: stage kt=0 into buffer 0
  {
#pragma unroll
    for (int p = 0; p < 8; ++p)
      *(uint4*)(lK[0] + ((p << 4) + krow) * LSTR + (cc0 << 3)) =
          *(const uint4*)(K_ws + (s0 + (p << 4) + krow) * 512 + (cc0 << 3));
#pragma unroll
    for (int p = 0; p < 2; ++p) {
      const int kq = (t >> 4) + (p << 3);
      float4 bv[4];
#pragma unroll
      for (int i = 0; i < 4; ++i)
        bv[i] = x4[xq_base + ((kq << 2) + i) * 128 + aq];
#pragma unroll
      for (int j = 0; j < 4; ++j) {
        _Float16 h[4];
#pragma unroll
        for (int i = 0; i < 4; ++i) h[i] = (_Float16)(((const float*)&bv[i])[j]);
        *(unsigned long long*)(lX[0] + ((aq << 2) + j) * LSTR + (kq << 2)) =
            *(const unsigned long long*)h;
      }
    }
  }

  for (int kt = 0; kt < 8; ++kt) {
    __syncthreads();
    const int cb = kt & 1, pb = cb ^ 1;

    // ---- prefetch kt+1 into registers (overlaps MFMA below)
    uint4 kR[8];
    float4 xR[8];
    if (kt < 7) {
      const int k1 = (kt + 1) << 6;
#pragma unroll
      for (int p = 0; p < 8; ++p)
        kR[p] = *(const uint4*)(K_ws + (s0 + (p << 4) + krow) * 512 + k1 + (cc0 << 3));
#pragma unroll
      for (int p = 0; p < 2; ++p) {
        const int kq = (t >> 4) + (p << 3);
#pragma unroll
        for (int i = 0; i < 4; ++i)
          xR[(p << 2) + i] = x4[xq_base + (k1 + (kq << 2) + i) * 128 + aq];
      }
    }

    // ---- compute on buffer cb: 2 k-steps of 32, 4x4 frags (wave tile 64x64)
#pragma unroll
    for (int ks = 0; ks < 2; ++ks) {
      half8 af[4], bf[4];
#pragma unroll
      for (int mb = 0; mb < 4; ++mb)
        af[mb] = *(const half8*)(lX[cb] + ((mb << 4) + fl) * LSTR + (ks << 5) + (q4 << 3));
#pragma unroll
      for (int nb = 0; nb < 4; ++nb)
        bf[nb] = *(const half8*)(lK[cb] + (n_w + (nb << 4) + fl) * LSTR + (ks << 5) + (q4 << 3));
#pragma unroll
      for (int mb = 0; mb < 4; ++mb)
#pragma unroll
        for (int nb = 0; nb < 4; ++nb)
          acc[mb][nb] = __builtin_amdgcn_mfma_f32_16x16x32_f16(af[mb], bf[nb], acc[mb][nb], 0, 0, 0);
    }

    // ---- write prefetched tile into the other buffer
    if (kt < 7) {
#pragma unroll
      for (int p = 0; p < 8; ++p)
        *(uint4*)(lK[pb] + ((p << 4) + krow) * LSTR + (cc0 << 3)) = kR[p];
#pragma unroll
      for (int p = 0; p < 2; ++p) {
        const int kq = (t >> 4) + (p << 3);
#pragma unroll
        for (int j = 0; j < 4; ++j) {
          _Float16 h[4];
#pragma unroll
          for (int i = 0; i < 4; ++i) h[i] = (_Float16)(((const float*)&xR[(p << 2) + i])[j]);
          *(unsigned long long*)(lX[pb] + ((aq << 2) + j) * LSTR + (kq << 2)) =
              *(const unsigned long long*)h;
        }
      }
    }
  }

  // ---- store: scrambled proj.T.reshape layout (validated R1-R8):
  // float idx = 262144*(s'>>5) + 512*(16*(s'&31)+bc) + a; regs = 4 consecutive a
  // -> one dwordx4 per frag.
#pragma unroll
  for (int nb = 0; nb < 4; ++nb) {
    const int sp = s0 + n_w + (nb << 4) + fl;
    const int rowbase = 262144 * (sp >> 5) + 512 * (16 * (sp & 31) + bc);
#pragma unroll
    for (int mb = 0; mb < 4; ++mb) {
      const int a = a0 + (mb << 4) + (q4 << 2);
      *(floatx4*)(out + rowbase + a) = acc[mb][nb];
    }
  }
}

extern "C" void kernel_launch(void* const* d_in, const int* in_sizes, int n_in,
                              void* d_out, int out_size, void* d_ws, size_t ws_size,
                              hipStream_t stream) {
  const float* x = (const float*)d_in[0];
  // d_in[1..3] (twiddles, filt_br) folded into the closed-form ramp IR.
  float* out = (float*)d_out;
  (void)in_sizes; (void)n_in; (void)out_size; (void)ws_size;

  _Float16* K_ws = (_Float16*)d_ws;  // 512 KB

  hipLaunchKernelGGL(build_K_kernel, dim3(128), dim3(256), 0, stream, K_ws);
  hipLaunchKernelGGL(gemm_fused_kernel, dim3(512), dim3(128), 0, stream,
                     K_ws, x, out);
}

// Round 10
// 81.750 us; speedup vs baseline: 1.0799x; 1.0799x over previous
//
#include <hip/hip_runtime.h>

typedef _Float16 half8 __attribute__((ext_vector_type(8)));
typedef float floatx4 __attribute__((ext_vector_type(4)));

#define PI_F 3.14159265358979323846f
#define LSTR 72

// ===================== Kernel 1: K f16 build from closed form (validated R7/R8):
// K[i][j] = c[(i-j)&1023]; c[0]=0.5, c[even]=0, c[odd d] = -1/(524288 sin^2(pi d/1024))
__global__ __launch_bounds__(256) void build_K_kernel(_Float16* __restrict__ K_ws) {
  const int base = ((int)blockIdx.x << 11) + ((int)threadIdx.x << 3);
  const int i = base >> 9;
  const int j0 = base & 511;
  _Float16 vals[8];
#pragma unroll
  for (int jj = 0; jj < 8; ++jj) {
    int d = (i - (j0 + jj)) & 1023;
    float v;
    if (d == 0) {
      v = 0.5f;
    } else if (d & 1) {
      float sn = __sinf((float)d * (PI_F / 1024.0f));
      v = -1.0f / (524288.0f * sn * sn);
    } else {
      v = 0.0f;
    }
    vals[jj] = (_Float16)v;
  }
  *(uint4*)(K_ws + base) = *(const uint4*)vals;
}

// ===================== Kernel 2: fused transpose+GEMM, double-buffered.
// A = x as [a][k] (in-register 4x4 transpose + XOR... cyclic-skew LDS layout),
// B = K rows [s'][k]. Block = 128 thr (2 waves), tile M(a)=64 x N(s')=64, BK=64;
// wave tile 64x32 (4x2 frags). Grid 1024 = exactly 4 blocks/CU (8 waves/CU,
// 2/SIMD — R8's proven occupancy, finer granularity: 4 independent barrier
// domains/CU). LDS dbuf 36.9 KB. Swizzle raw%8 = at: st-siblings (same x slice)
// share the XCD. lX uses chunk-skew (c+aq)&7 to kill the 8-way b64 write conflict.
__global__ __launch_bounds__(128, 2) void gemm_fused_kernel(
    const _Float16* __restrict__ K_ws, const float* __restrict__ x,
    float* __restrict__ out) {
  __shared__ __align__(16) _Float16 lX[2][64 * LSTR];  // [a][k], skewed chunks
  __shared__ __align__(16) _Float16 lK[2][64 * LSTR];  // [s'][k], linear

  const int t = threadIdx.x;
  const int raw = blockIdx.x;
  // raw = st*128 + bc*8 + at  ->  raw%8 = at (XCD id shared by all st-siblings)
  const int at = raw & 7;
  const int bc = (raw >> 3) & 15;
  const int st = raw >> 7;
  const int a0 = at << 6, s0 = st << 6;

  const int w = t >> 6, lane = t & 63;
  const int n_w = w << 5;  // wave s'-offset: 0 / 32
  const int fl = lane & 15, q4 = lane >> 4;

  // x staging: a-quad aq (t&15), k-quads kq = (t>>4) + p*8 (p=0,1)
  const int aq = t & 15;
  const int kq0 = t >> 4;

  const float4* __restrict__ x4 = (const float4*)x;
  const int xq_base = bc * 65536 + (a0 >> 2);  // float4 index base

  floatx4 acc[4][2] = {};

  // ---- helpers ----
#define STAGE_K(buf, kofs)                                                      \
  {                                                                             \
    _Pragma("unroll") for (int p = 0; p < 4; ++p) {                             \
      int ci = t + (p << 7);                                                    \
      int row = ci >> 3, cc = ci & 7;                                           \
      *(uint4*)(lK[buf] + row * LSTR + (cc << 3)) =                             \
          *(const uint4*)(K_ws + (s0 + row) * 512 + (kofs) + (cc << 3));        \
    }                                                                           \
  }

  // write 4 f16 (k-quad kq, a-row 4*aq+j) with chunk skew ((kq>>1)+aq)&7
#define XPUT(buf, kq, j, h4)                                                    \
  *(unsigned long long*)(lX[buf] + ((aq << 2) + (j)) * LSTR +                   \
                         ((((kq) >> 1) + aq) & 7) * 8 + ((kq) & 1) * 4) =       \
      *(const unsigned long long*)(h4)

  // ---- prologue: stage kt=0 into buffer 0
  {
    STAGE_K(0, 0)
#pragma unroll
    for (int p = 0; p < 2; ++p) {
      const int kq = kq0 + (p << 3);
      float4 bv[4];
#pragma unroll
      for (int i = 0; i < 4; ++i) bv[i] = x4[xq_base + ((kq << 2) + i) * 128 + aq];
#pragma unroll
      for (int j = 0; j < 4; ++j) {
        _Float16 h[4];
#pragma unroll
        for (int i = 0; i < 4; ++i) h[i] = (_Float16)(((const float*)&bv[i])[j]);
        XPUT(0, kq, j, h);
      }
    }
  }

  for (int kt = 0; kt < 8; ++kt) {
    __syncthreads();
    const int cb = kt & 1, pb = cb ^ 1;

    // ---- prefetch kt+1 into registers (overlaps MFMA below)
    uint4 kR[4];
    float4 xR[8];
    if (kt < 7) {
      const int k1 = (kt + 1) << 6;
#pragma unroll
      for (int p = 0; p < 4; ++p) {
        int ci = t + (p << 7);
        int row = ci >> 3, cc = ci & 7;
        kR[p] = *(const uint4*)(K_ws + (s0 + row) * 512 + k1 + (cc << 3));
      }
#pragma unroll
      for (int p = 0; p < 2; ++p) {
        const int kq = kq0 + (p << 3);
#pragma unroll
        for (int i = 0; i < 4; ++i)
          xR[(p << 2) + i] = x4[xq_base + (k1 + (kq << 2) + i) * 128 + aq];
      }
    }

    // ---- compute on buffer cb: 2 k-steps of 32, 4x2 frags (wave tile 64a x 32s')
#pragma unroll
    for (int ks = 0; ks < 2; ++ks) {
      half8 af[4], bf[2];
#pragma unroll
      for (int mb = 0; mb < 4; ++mb) {
        const int m = (mb << 4) + fl;
        const int ch = ((ks << 2) + q4 + (m >> 2)) & 7;  // skewed chunk
        af[mb] = *(const half8*)(lX[cb] + m * LSTR + (ch << 3));
      }
#pragma unroll
      for (int nb = 0; nb < 2; ++nb)
        bf[nb] = *(const half8*)(lK[cb] + (n_w + (nb << 4) + fl) * LSTR + (ks << 5) + (q4 << 3));
#pragma unroll
      for (int mb = 0; mb < 4; ++mb)
#pragma unroll
        for (int nb = 0; nb < 2; ++nb)
          acc[mb][nb] = __builtin_amdgcn_mfma_f32_16x16x32_f16(af[mb], bf[nb], acc[mb][nb], 0, 0, 0);
    }

    // ---- write prefetched tile into the other buffer
    if (kt < 7) {
#pragma unroll
      for (int p = 0; p < 4; ++p) {
        int ci = t + (p << 7);
        int row = ci >> 3, cc = ci & 7;
        *(uint4*)(lK[pb] + row * LSTR + (cc << 3)) = kR[p];
      }
#pragma unroll
      for (int p = 0; p < 2; ++p) {
        const int kq = kq0 + (p << 3);
#pragma unroll
        for (int j = 0; j < 4; ++j) {
          _Float16 h[4];
#pragma unroll
          for (int i = 0; i < 4; ++i) h[i] = (_Float16)(((const float*)&xR[(p << 2) + i])[j]);
          XPUT(pb, kq, j, h);
        }
      }
    }
  }

  // ---- store: scrambled proj.T.reshape layout (validated R1-R9):
  // float idx = 262144*(s'>>5) + 512*(16*(s'&31)+bc) + a; reg-quad = 4 consecutive a
#pragma unroll
  for (int nb = 0; nb < 2; ++nb) {
    const int sp = s0 + n_w + (nb << 4) + fl;
    const int rowbase = 262144 * (sp >> 5) + 512 * (16 * (sp & 31) + bc);
#pragma unroll
    for (int mb = 0; mb < 4; ++mb) {
      const int a = a0 + (mb << 4) + (q4 << 2);
      *(floatx4*)(out + rowbase + a) = acc[mb][nb];
    }
  }
#undef STAGE_K
#undef XPUT
}

extern "C" void kernel_launch(void* const* d_in, const int* in_sizes, int n_in,
                              void* d_out, int out_size, void* d_ws, size_t ws_size,
                              hipStream_t stream) {
  const float* x = (const float*)d_in[0];
  // d_in[1..3] (twiddles, filt_br) folded into the closed-form ramp IR.
  float* out = (float*)d_out;
  (void)in_sizes; (void)n_in; (void)out_size; (void)ws_size;

  _Float16* K_ws = (_Float16*)d_ws;  // 512 KB

  hipLaunchKernelGGL(build_K_kernel, dim3(128), dim3(256), 0, stream, K_ws);
  hipLaunchKernelGGL(gemm_fused_kernel, dim3(1024), dim3(128), 0, stream,
                     K_ws, x, out);
}